// Round 11
// baseline (168.527 us; speedup 1.0000x reference)
//
#include <hip/hip_runtime.h>
#include <hip/hip_bf16.h>

using sh8   = __attribute__((ext_vector_type(8))) short;
using f32x4 = __attribute__((ext_vector_type(4))) float;

#define DEV __device__ __forceinline__

DEV float leaky(float x) { return x >= 0.f ? x : 0.2f * x; }

DEV unsigned short f2bf(float f) {  // round-to-nearest-even f32 -> bf16 bits
  unsigned u = __float_as_uint(f);
  u += 0x7FFF + ((u >> 16) & 1);
  return (unsigned short)(u >> 16);
}
DEV float bf2f(unsigned short b) { return __uint_as_float(((unsigned)b) << 16); }

// ---------------- weight packing (templated: all dims pow2 -> shifts) ----------------
template<int Cout, int Cin>
DEV void pack7_body(const float* __restrict__ w, unsigned short* __restrict__ wp, int blk) {
  constexpr long plane = (long)(Cin >> 5) * Cout * 32;
  int tid = blk * 256 + threadIdx.x;
  if (tid >= Cout * Cin) return;
  int co = tid / Cin, ci = tid - co * Cin;
  const float* src = w + (long)tid * 7;
  unsigned short* dst = wp + ((long)(ci >> 5) * Cout + co) * 32 + (ci & 31);
  #pragma unroll
  for (int k = 0; k < 7; ++k) dst[k * plane] = f2bf(src[k]);
}
template<int Cout, int Cin>
DEV void packph_body(const float* __restrict__ w, unsigned short* __restrict__ wp, int blk) {
  constexpr long plane = (long)(Cin >> 5) * Cout * 32;
  int tid = blk * 256 + threadIdx.x;
  if (tid >= Cout * Cin) return;
  int co = tid / Cin, ci = tid - co * Cin;
  float wk[7];
  #pragma unroll
  for (int k = 0; k < 7; ++k) wk[k] = w[(long)tid * 7 + k];
  unsigned short* dst = wp + ((long)(ci >> 5) * Cout + co) * 32 + (ci & 31);
  #pragma unroll
  for (int p = 0; p < 4; ++p) {
    #pragma unroll
    for (int d = 0; d < 3; ++d) {
      float s = 0.f;
      #pragma unroll
      for (int k = 0; k < 7; ++k) if (((p + k + 1) >> 2) == d) s += wk[k];
      dst[(p * 3 + d) * plane] = f2bf(s);
    }
  }
}
__global__ __launch_bounds__(256)
void pack_all(const float* __restrict__ w1, const float* __restrict__ w2,
              const float* __restrict__ w3, const float* __restrict__ w4,
              unsigned short* __restrict__ wbuf) {
  int blk = blockIdx.x;
  if (blk < 2048)      pack7_body<512, 1024>(w1, wbuf, blk);
  else if (blk < 2560) packph_body<256, 512>(w2, wbuf + 3670016, blk - 2048);
  else if (blk < 2688) packph_body<128, 256>(w3, wbuf + 5242880, blk - 2560);
  else                 packph_body<64, 128>(w4, wbuf + 5636096, blk - 2688);
}

// ---------------- embed v6: direct-load MFMA GEMM (no input LDS bounce) ----------------
// Block = 64 rows (half a (b,band)); 4 waves x 16-row tiles. Grid 1024.
// A-fragments loaded straight from x (8 consecutive f32 per lane per k-step).
// ctx written as 2 deterministic partials per channel (summed in gemm_p<SUM2=1>).
__global__ __launch_bounds__(256)
void embed_mfma(const float* __restrict__ x, const float* __restrict__ ew,
                const float* __restrict__ eb, unsigned short* __restrict__ encbf,
                float* __restrict__ part) {
  __shared__ unsigned short W16[257 * 16];   // [p][f], f>=8 zeroed
  __shared__ float ctxred[4][8];
  const int tid = threadIdx.x;

  for (int i = tid; i < 257 * 16; i += 256) {
    int p = i >> 4, f = i & 15;
    W16[i] = (f < 8) ? f2bf(ew[p * 8 + f]) : (unsigned short)0;
  }
  __syncthreads();

  const int w = tid >> 6, lane = tid & 63;
  const int m = lane & 15, g = lane >> 4;

  sh8 breg[8];
  #pragma unroll
  for (int kk = 0; kk < 8; ++kk) {
    #pragma unroll
    for (int j = 0; j < 8; ++j)
      breg[kk][j] = (short)W16[(kk * 32 + g * 8 + j) * 16 + m];
  }
  const float w256 = bf2f(W16[256 * 16 + m]);
  const float ebf = (m < 8) ? eb[m] : 0.f;

  const int bid = blockIdx.x;                // 1024 blocks of 64 rows
  const long row0 = (long)bid * 64;
  const int b = bid >> 8, band = (bid >> 1) & 127, half = bid & 1;
  const int t0 = half * 64 + w * 16;

  // ---- load all 64 A-elements (fully static -> 64 loads in flight) ----
  const float* xp = x + (row0 + w * 16 + m) * 257 + g * 8;
  float vals[8][8];
  #pragma unroll
  for (int kk = 0; kk < 8; ++kk) {
    #pragma unroll
    for (int j = 0; j < 8; ++j)
      vals[kk][j] = xp[kk * 32 + j];
  }
  f32x4 acc = {0.f, 0.f, 0.f, 0.f};
  #pragma unroll
  for (int kk = 0; kk < 8; ++kk) {
    sh8 afr;
    #pragma unroll
    for (int j = 0; j < 8; ++j) afr[j] = (short)f2bf(vals[kk][j]);
    acc = __builtin_amdgcn_mfma_f32_16x16x32_bf16(afr, breg[kk], acc, 0, 0, 0);
  }

  // k=256 rank-1 + bias (m>=8 lanes produce exact 0: W cols zeroed, ebf=0)
  const float* xq = x + (row0 + w * 16 + g * 4) * 257 + 256;
  float ctx_acc = 0.f;
  unsigned short pk[4];
  #pragma unroll
  for (int r = 0; r < 4; ++r) {
    float e = acc[r] + xq[(long)r * 257] * w256 + ebf;
    pk[r] = f2bf(e);
    ctx_acc += e;
  }
  if (m < 8) {
    long o = ((long)b * 1024 + m * 128 + band) * 128 + t0 + g * 4;
    *(ushort4*)(encbf + o) = make_ushort4(pk[0], pk[1], pk[2], pk[3]);
  }

  // ctx partial: reduce over g (16 rows of this wave), then over 4 waves
  ctx_acc += __shfl_xor(ctx_acc, 16);
  ctx_acc += __shfl_xor(ctx_acc, 32);
  if (lane < 8) ctxred[w][lane] = ctx_acc;
  __syncthreads();
  if (tid < 8) {
    float sv = ctxred[0][tid] + ctxred[1][tid] + ctxred[2][tid] + ctxred[3][tid];
    part[((b * 1024 + tid * 128 + band) << 1) + half] = sv;
  }
}

// ---------------- split-K gemm: partial y = h(4,1024) @ w[k-chunk] ----------------
template<int SUM2>
__global__ void gemm_p(const float* __restrict__ h, const float* __restrict__ w,
                       float* __restrict__ gpart) {
  __shared__ float hl[4][128];
  __shared__ float red[8][4][32];
  const int kc = blockIdx.y, jb = blockIdx.x, k0 = kc * 128;
  for (int i = threadIdx.x; i < 512; i += 256) {
    int bb = i >> 7, kk = i & 127;
    float v;
    if (SUM2) {
      int base = ((bb << 10) + k0 + kk) << 1;
      v = h[base] + h[base + 1];
    } else {
      v = h[(bb << 10) + k0 + kk];
    }
    hl[bb][kk] = v;
  }
  __syncthreads();
  const int jl = threadIdx.x & 31, kq = threadIdx.x >> 5;
  const int j = jb * 32 + jl;
  float a0 = 0, a1 = 0, a2 = 0, a3 = 0;
  const float* wp = w + (long)(k0 + kq * 16) * 1024 + j;
  #pragma unroll
  for (int k = 0; k < 16; ++k) {
    float wv = wp[(long)k * 1024];
    a0 += hl[0][kq * 16 + k] * wv;
    a1 += hl[1][kq * 16 + k] * wv;
    a2 += hl[2][kq * 16 + k] * wv;
    a3 += hl[3][kq * 16 + k] * wv;
  }
  red[kq][0][jl] = a0; red[kq][1][jl] = a1; red[kq][2][jl] = a2; red[kq][3][jl] = a3;
  __syncthreads();
  if (threadIdx.x < 128) {
    int bb = threadIdx.x >> 5, j2 = threadIdx.x & 31;
    float s = 0;
    #pragma unroll
    for (int q = 0; q < 8; ++q) s += red[q][bb][j2];
    gpart[((long)kc * 4 + bb) * 1024 + jb * 32 + j2] = s;
  }
}

// ---------------- sum split-K partials + bias + leaky + layernorm ----------------
__global__ void lnsum_kernel(const float* __restrict__ gpart, const float* __restrict__ bias,
                             const float* __restrict__ g, const float* __restrict__ be,
                             float* __restrict__ out) {
  int b = blockIdx.x;
  __shared__ float buf[1024];
  __shared__ float rs[4], rq[4];
  float s = 0, q = 0;
  #pragma unroll
  for (int i = 0; i < 4; ++i) {
    int j = threadIdx.x + i * 256;
    float v = bias[j];
    #pragma unroll
    for (int kc = 0; kc < 8; ++kc) v += gpart[((long)kc * 4 + b) * 1024 + j];
    v = leaky(v);
    buf[j] = v; s += v; q += v * v;
  }
  #pragma unroll
  for (int off = 32; off; off >>= 1) { s += __shfl_down(s, off); q += __shfl_down(q, off); }
  int wid = threadIdx.x >> 6, lane = threadIdx.x & 63;
  if (lane == 0) { rs[wid] = s; rq[wid] = q; }
  __syncthreads();
  float S = rs[0] + rs[1] + rs[2] + rs[3];
  float Q = rq[0] + rq[1] + rq[2] + rq[3];
  float mean = S * (1.f / 1024.f);
  float var = Q * (1.f / 1024.f) - mean * mean;
  float rstd = rsqrtf(var + 1e-5f);
  #pragma unroll
  for (int i = 0; i < 4; ++i) {
    int j = threadIdx.x + i * 256;
    out[b * 1024 + j] = (buf[j] - mean) * rstd * g[j] + be[j];
  }
}

// ---------------- final: ctx_out = sum partials + bias ----------------
__global__ void fin_kernel(const float* __restrict__ gpart, const float* __restrict__ bias,
                           float* __restrict__ out) {
  int i = blockIdx.x * 256 + threadIdx.x;   // 4096
  int b = i >> 10, j = i & 1023;
  float v = bias[j];
  #pragma unroll
  for (int kc = 0; kc < 8; ++kc) v += gpart[((long)kc * 4 + b) * 1024 + j];
  out[i] = v;
}

// ---------------- implicit-GEMM conv1d via MFMA bf16 (stage 1, UPS=1) ----------------
template<int UPS, int SPLITK>
__global__ __launch_bounds__(256, 2)
void conv_mfma(const unsigned short* __restrict__ act,
               const unsigned short* __restrict__ wpack,
               float* __restrict__ outp,
               int Cin, int Cout, int Tout) {
  constexpr int NC = (UPS == 1) ? 70 : 18;
  const int Tin = Tout / UPS;
  const int cpb = Cin / SPLITK;
  const int ncib = cpb >> 5;
  const int nCibTot = Cin >> 5;
  const int nco = Cout >> 6, nt = Tout >> 6;

  int bid = blockIdx.x;
  const int sk = bid % SPLITK; bid /= SPLITK;
  const int tt = bid % nt;  bid /= nt;
  const int cot = bid % nco; bid /= nco;
  const int b = bid;
  const int t0 = tt << 6, co0 = cot << 6;
  const int ci0 = sk * cpb;

  extern __shared__ unsigned short lin[];    // [ncib][NC][40]

  const unsigned short* actb = act + ((long)b * Cin + ci0) * Tin;
  const int u_base = (UPS == 1) ? (t0 - 3) : ((t0 >> 2) - 1);
  const int total = cpb * NC;
  for (int i = threadIdx.x; i < total; i += 256) {
    int ci = i / NC, ul = i - ci * NC;
    int u = u_base + ul;
    unsigned short v = 0;
    if (u >= 0 && u < Tin) v = actb[(long)ci * Tin + u];
    lin[((ci >> 5) * NC + ul) * 40 + (ci & 31)] = v;
  }
  __syncthreads();

  const int lane = threadIdx.x & 63, w = threadIdx.x >> 6;
  const int m = lane & 15, g = lane >> 4;

  int boff[28];
  #pragma unroll
  for (int s = 0; s < 4; ++s) {
    #pragma unroll
    for (int k = 0; k < 7; ++k) {
      int row = (UPS == 1) ? (s * 16 + m + k)
                           : (s * 4 + ((m + k + 9) >> 2) - 2);
      boff[s * 7 + k] = row * 40 + g * 8;
    }
  }

  const long wlane = ((long)(co0 + w * 16 + m) * 4 + g) * 8;

  f32x4 acc[4];
  #pragma unroll
  for (int s = 0; s < 4; ++s) { acc[s][0] = 0.f; acc[s][1] = 0.f; acc[s][2] = 0.f; acc[s][3] = 0.f; }

  for (int cib = 0; cib < ncib; ++cib) {
    const unsigned short* lb = lin + cib * (NC * 40);
    const int cg = (ci0 >> 5) + cib;
    sh8 a[7];
    #pragma unroll
    for (int k = 0; k < 7; ++k)
      a[k] = *(const sh8*)(wpack + (long)(k * nCibTot + cg) * Cout * 32 + wlane);
    #pragma unroll
    for (int k = 0; k < 7; ++k) {
      #pragma unroll
      for (int s = 0; s < 4; ++s) {
        sh8 bfr = *(const sh8*)(lb + boff[s * 7 + k]);
        acc[s] = __builtin_amdgcn_mfma_f32_16x16x32_bf16(a[k], bfr, acc[s], 0, 0, 0);
      }
    }
  }

  float* op = outp + (((long)sk * 4 + b) * Cout + (co0 + w * 16 + g * 4)) * (long)Tout + t0 + m;
  #pragma unroll
  for (int r = 0; r < 4; ++r) {
    #pragma unroll
    for (int s = 0; s < 4; ++s)
      op[(long)r * Tout + s * 16] = acc[s][r];
  }
}

// ---------------- phase-decomposed conv with FUSED bn-apply in staging ----------------
template<int SPLITK>
__global__ __launch_bounds__(256, 2)
void conv_ph(const float* __restrict__ csum_in, const float* __restrict__ sp,
             const float* __restrict__ g, const float* __restrict__ be,
             const unsigned short* __restrict__ wpack,
             float* __restrict__ outp,
             int Cin, int Cout, int Tin) {
  const int Tout = Tin << 2;
  const int cpb = Cin / SPLITK;
  const int ncib = cpb >> 5;
  const int nCibTot = Cin >> 5;
  const int nco = Cout >> 6, ntu = Tin >> 6;

  int bid = blockIdx.x;
  const int sk = bid % SPLITK; bid /= SPLITK;
  const int tu = bid % ntu; bid /= ntu;
  const int cot = bid % nco; bid /= nco;
  const int b = bid;
  const int u0 = tu << 6, co0 = cot << 6;
  const int ci0 = sk * cpb;

  extern __shared__ unsigned short lin[];    // [ncib][66][40]
  __shared__ float ssc[64], ssh[64];

  if (threadIdx.x < cpb) {
    int c = ci0 + threadIdx.x;
    float S = sp[c * 4] + sp[c * 4 + 1] + sp[c * 4 + 2] + sp[c * 4 + 3];
    float Q = sp[Cin * 4 + c * 4] + sp[Cin * 4 + c * 4 + 1] + sp[Cin * 4 + c * 4 + 2] + sp[Cin * 4 + c * 4 + 3];
    float n = 4.f * (float)Tin;
    float mean = S / n;
    float var = Q / n - mean * mean;
    float sc = g[c] * rsqrtf(var + 1e-5f);
    ssc[threadIdx.x] = sc;
    ssh[threadIdx.x] = be[c] - mean * sc;
  }
  __syncthreads();

  const float* csb = csum_in + ((long)b * Cin + ci0) * Tin;
  const int total = cpb * 66;
  for (int i = threadIdx.x; i < total; i += 256) {
    int ci = i / 66, r = i - ci * 66;
    int u = u0 - 1 + r;
    unsigned short v = 0;
    if (u >= 0 && u < Tin) {
      float t = csb[(long)ci * Tin + u];
      v = f2bf(leaky(t * ssc[ci] + ssh[ci]));
    }
    lin[((ci >> 5) * 66 + r) * 40 + (ci & 31)] = v;
  }
  __syncthreads();

  const int lane = threadIdx.x & 63, w = threadIdx.x >> 6;
  const int m = lane & 15, g2 = lane >> 4;

  int boff[4][3];
  #pragma unroll
  for (int s = 0; s < 4; ++s)
    #pragma unroll
    for (int d = 0; d < 3; ++d)
      boff[s][d] = (s * 16 + m + d) * 40 + g2 * 8;

  const long wlane = ((long)(co0 + w * 16 + m)) * 32 + g2 * 8;

  f32x4 acc[4][4];                           // [s][p]
  #pragma unroll
  for (int s = 0; s < 4; ++s)
    #pragma unroll
    for (int p = 0; p < 4; ++p) { acc[s][p][0] = 0.f; acc[s][p][1] = 0.f; acc[s][p][2] = 0.f; acc[s][p][3] = 0.f; }

  for (int cib = 0; cib < ncib; ++cib) {
    const unsigned short* lb = lin + cib * (66 * 40);
    const int cg = (ci0 >> 5) + cib;
    sh8 a[12];
    #pragma unroll
    for (int pd = 0; pd < 12; ++pd)
      a[pd] = *(const sh8*)(wpack + ((long)(pd * nCibTot + cg) * Cout) * 32 + wlane);
    #pragma unroll
    for (int s = 0; s < 4; ++s) {
      sh8 b0 = *(const sh8*)(lb + boff[s][0]);
      sh8 b1 = *(const sh8*)(lb + boff[s][1]);
      sh8 b2 = *(const sh8*)(lb + boff[s][2]);
      acc[s][0] = __builtin_amdgcn_mfma_f32_16x16x32_bf16(a[0],  b0, acc[s][0], 0, 0, 0);
      acc[s][0] = __builtin_amdgcn_mfma_f32_16x16x32_bf16(a[1],  b1, acc[s][0], 0, 0, 0);
      acc[s][1] = __builtin_amdgcn_mfma_f32_16x16x32_bf16(a[3],  b0, acc[s][1], 0, 0, 0);
      acc[s][1] = __builtin_amdgcn_mfma_f32_16x16x32_bf16(a[4],  b1, acc[s][1], 0, 0, 0);
      acc[s][1] = __builtin_amdgcn_mfma_f32_16x16x32_bf16(a[5],  b2, acc[s][1], 0, 0, 0);
      acc[s][2] = __builtin_amdgcn_mfma_f32_16x16x32_bf16(a[6],  b0, acc[s][2], 0, 0, 0);
      acc[s][2] = __builtin_amdgcn_mfma_f32_16x16x32_bf16(a[7],  b1, acc[s][2], 0, 0, 0);
      acc[s][2] = __builtin_amdgcn_mfma_f32_16x16x32_bf16(a[8],  b2, acc[s][2], 0, 0, 0);
      acc[s][3] = __builtin_amdgcn_mfma_f32_16x16x32_bf16(a[10], b1, acc[s][3], 0, 0, 0);
      acc[s][3] = __builtin_amdgcn_mfma_f32_16x16x32_bf16(a[11], b2, acc[s][3], 0, 0, 0);
    }
  }

  float* op = outp + (((long)sk * 4 + b) * Cout + (co0 + w * 16 + g2 * 4)) * (long)Tout;
  #pragma unroll
  for (int r = 0; r < 4; ++r) {
    #pragma unroll
    for (int s = 0; s < 4; ++s) {
      float4 v4 = make_float4(acc[s][0][r], acc[s][1][r], acc[s][2][r], acc[s][3][r]);
      *(float4*)(op + (long)r * Tout + ((u0 + s * 16 + m) << 2)) = v4;
    }
  }
}

// ---------------- bn stats: sum split-K (write csum) + per-(c,b) partial stats ----------------
__global__ void bnsum_kernel(const float* __restrict__ p, float* __restrict__ sp,
                             float* __restrict__ csum, int C, int T, int SK) {
  int c = blockIdx.x, b = blockIdx.y;
  long stride = (long)4 * C * T;
  const float* r = p + ((long)b * C + c) * T;
  float* cw = csum + ((long)b * C + c) * T;
  float s = 0, q = 0;
  for (int t = threadIdx.x; t < T; t += 256) {
    float v = r[t];
    for (int k = 1; k < SK; ++k) v += r[t + k * stride];
    cw[t] = v;
    s += v; q += v * v;
  }
  #pragma unroll
  for (int off = 32; off; off >>= 1) { s += __shfl_down(s, off); q += __shfl_down(q, off); }
  __shared__ float rs[4], rq[4];
  int wid = threadIdx.x >> 6, lane = threadIdx.x & 63;
  if (lane == 0) { rs[wid] = s; rq[wid] = q; }
  __syncthreads();
  if (threadIdx.x == 0) {
    sp[c * 4 + b] = rs[0] + rs[1] + rs[2] + rs[3];
    sp[C * 4 + c * 4 + b] = rq[0] + rq[1] + rq[2] + rq[3];
  }
}

// ---------------- final conv: phase-decomposed 3-tap, FUSED bn-apply staging ----------------
__global__ __launch_bounds__(256)
void conv5_kernel(const float* __restrict__ csum_in, const float* __restrict__ sp,
                  const float* __restrict__ g, const float* __restrict__ be,
                  const float* __restrict__ wgt, const float* __restrict__ bias,
                  float* __restrict__ out, int Tout) {
  __shared__ unsigned short sv[64 * 66];
  __shared__ float wph[64 * 13];
  __shared__ float ssc[64], ssh[64];

  const int b = blockIdx.y;
  const int u0 = blockIdx.x * 64;
  const int Tin = Tout >> 2;
  const int tid = threadIdx.x;

  {
    int ci = tid >> 2, pp = tid & 3;
    float s0 = 0, s1 = 0, s2 = 0;
    #pragma unroll
    for (int k = 0; k < 7; ++k) {
      int d = (pp - 3 + k + 4) >> 2;
      float wv = wgt[ci * 7 + k];
      if (d == 0) s0 += wv; else if (d == 1) s1 += wv; else s2 += wv;
    }
    wph[ci * 13 + pp * 3 + 0] = s0;
    wph[ci * 13 + pp * 3 + 1] = s1;
    wph[ci * 13 + pp * 3 + 2] = s2;
  }
  if (tid < 64) {
    float S = sp[tid * 4] + sp[tid * 4 + 1] + sp[tid * 4 + 2] + sp[tid * 4 + 3];
    float Q = sp[256 + tid * 4] + sp[256 + tid * 4 + 1] + sp[256 + tid * 4 + 2] + sp[256 + tid * 4 + 3];
    float n = 4.f * (float)Tin;
    float mean = S / n;
    float var = Q / n - mean * mean;
    float sc = g[tid] * rsqrtf(var + 1e-5f);
    ssc[tid] = sc;
    ssh[tid] = be[tid] - mean * sc;
  }
  __syncthreads();

  const float* inb = csum_in + (long)b * 64 * Tin;
  for (int i = tid; i < 64 * 66; i += 256) {
    int ci = i / 66, uu = i - ci * 66;
    int u = u0 - 1 + uu;
    unsigned short v = 0;
    if (u >= 0 && u < Tin) {
      float t = inb[(long)ci * Tin + u];
      v = f2bf(leaky(t * ssc[ci] + ssh[ci]));
    }
    sv[ci * 66 + uu] = v;
  }
  __syncthreads();

  const int ul = tid >> 2;
  const int chunk = tid & 3;
  float a0 = 0, a1 = 0, a2 = 0, a3 = 0;
  #pragma unroll
  for (int cc = 0; cc < 16; ++cc) {
    int ci = chunk * 16 + cc;
    float v0 = bf2f(sv[ci * 66 + ul]);
    float v1 = bf2f(sv[ci * 66 + ul + 1]);
    float v2 = bf2f(sv[ci * 66 + ul + 2]);
    const float* wp = wph + ci * 13;
    a0 += v0 * wp[0] + v1 * wp[1];
    a1 += v0 * wp[3] + v1 * wp[4] + v2 * wp[5];
    a2 += v0 * wp[6] + v1 * wp[7] + v2 * wp[8];
    a3 += v1 * wp[10] + v2 * wp[11];
  }
  #pragma unroll
  for (int msk = 1; msk <= 2; msk <<= 1) {
    a0 += __shfl_xor(a0, msk);
    a1 += __shfl_xor(a1, msk);
    a2 += __shfl_xor(a2, msk);
    a3 += __shfl_xor(a3, msk);
  }
  if (chunk == 0) {
    float bv = bias[0];
    float4 r = make_float4(a0 + bv, a1 + bv, a2 + bv, a3 + bv);
    *(float4*)(out + (long)b * Tout + (long)(u0 + ul) * 4) = r;
  }
}

extern "C" void kernel_launch(void* const* d_in, const int* in_sizes, int n_in,
                              void* d_out, int out_size, void* d_ws, size_t ws_size,
                              hipStream_t stream) {
  const float* x     = (const float*)d_in[0];
  // d_in[1] = atoms: dead (sparse_code result unused by outputs)
  const float* ew    = (const float*)d_in[2];
  const float* eb    = (const float*)d_in[3];
  const float* w1    = (const float*)d_in[4];
  const float* b1    = (const float*)d_in[5];
  const float* g1    = (const float*)d_in[6];
  const float* be1   = (const float*)d_in[7];
  const float* w2    = (const float*)d_in[8];
  const float* b2    = (const float*)d_in[9];
  const float* g2    = (const float*)d_in[10];
  const float* be2   = (const float*)d_in[11];
  const float* w3    = (const float*)d_in[12];
  const float* b3    = (const float*)d_in[13];
  const float* up_w1 = (const float*)d_in[14];
  const float* up_b1 = (const float*)d_in[15];
  const float* bn_g1 = (const float*)d_in[16];
  const float* bn_b1 = (const float*)d_in[17];
  const float* up_w2 = (const float*)d_in[18];
  const float* up_b2 = (const float*)d_in[19];
  const float* bn_g2 = (const float*)d_in[20];
  const float* bn_b2 = (const float*)d_in[21];
  const float* up_w3 = (const float*)d_in[22];
  const float* up_b3 = (const float*)d_in[23];
  const float* bn_g3 = (const float*)d_in[24];
  const float* bn_b3 = (const float*)d_in[25];
  const float* up_w4 = (const float*)d_in[26];
  const float* up_b4 = (const float*)d_in[27];
  const float* bn_g4 = (const float*)d_in[28];
  const float* bn_b4 = (const float*)d_in[29];
  const float* up_w5 = (const float*)d_in[30];
  const float* up_b5 = (const float*)d_in[31];

  float* out = (float*)d_out;              // [0,131072) = y, [131072,135168) = ctx_out

  float* ws = (float*)d_ws;
  float* part   = ws;                      // 8192
  float* gpart  = part + 8192;             // 32768
  float* t2     = gpart + 32768;           // 4096
  float* statsp = t2 + 4096;               // 4096
  float* csum   = statsp + 4096;           // 2097152
  float* pbuf   = csum + 2097152;          // 4194304
  unsigned short* encbf = (unsigned short*)(pbuf + 4194304);  // 524288 u16
  unsigned short* wbuf  = encbf + 524288;  // 5734400 u16

  // weight packing + embed (direct-load MFMA, fused ctx partials)
  pack_all<<<2720, 256, 0, stream>>>(up_w1, up_w2, up_w3, up_w4, wbuf);
  embed_mfma<<<1024, 256, 0, stream>>>(x, ew, eb, encbf, part);

  // ctx MLP (split-K gemms, deterministic partial sums; first gemm folds ctx 2-partials)
  gemm_p<1><<<dim3(32, 8), 256, 0, stream>>>(part, w1, gpart);
  lnsum_kernel<<<4, 256, 0, stream>>>(gpart, b1, g1, be1, t2);
  gemm_p<0><<<dim3(32, 8), 256, 0, stream>>>(t2, w2, gpart);
  lnsum_kernel<<<4, 256, 0, stream>>>(gpart, b2, g2, be2, t2);
  gemm_p<0><<<dim3(32, 8), 256, 0, stream>>>(t2, w3, gpart);
  fin_kernel<<<16, 256, 0, stream>>>(gpart, b3, out + 131072);

  // ---- stage 1: (4,1024,128) -> (4,512,128), UPS=1, SK=8 ----
  conv_mfma<1, 8><<<512, 256, 22400, stream>>>(encbf, wbuf, pbuf, 1024, 512, 128);
  bnsum_kernel<<<dim3(512, 4), 256, 0, stream>>>(pbuf, statsp, csum, 512, 128, 8);

  // ---- stage 2: (4,512,128) -bn+ph-> (4,256,512), SK=8 ----
  conv_ph<8><<<256, 256, 10560, stream>>>(csum, statsp, bn_g1, bn_b1, wbuf + 3670016, pbuf, 512, 256, 128);
  bnsum_kernel<<<dim3(256, 4), 256, 0, stream>>>(pbuf, statsp, csum, 256, 512, 8);

  // ---- stage 3: (4,256,512) -bn+ph-> (4,128,2048), SK=4 ----
  conv_ph<4><<<256, 256, 10560, stream>>>(csum, statsp, bn_g2, bn_b2, wbuf + 5242880, pbuf, 256, 128, 512);
  bnsum_kernel<<<dim3(128, 4), 256, 0, stream>>>(pbuf, statsp, csum, 128, 2048, 4);

  // ---- stage 4: (4,128,2048) -bn+ph-> (4,64,8192), SK=2 ----
  conv_ph<2><<<256, 256, 10560, stream>>>(csum, statsp, bn_g3, bn_b3, wbuf + 5636096, pbuf, 128, 64, 2048);
  bnsum_kernel<<<dim3(64, 4), 256, 0, stream>>>(pbuf, statsp, csum, 64, 8192, 2);

  // ---- stage 5: (4,64,8192) -bn+ph-> (4,1,32768) ----
  conv5_kernel<<<dim3(128, 4), 256, 0, stream>>>(csum, statsp, bn_g4, bn_b4, up_w5, up_b5, out, 32768);
}

// Round 12
// 147.559 us; speedup vs baseline: 1.1421x; 1.1421x over previous
//
#include <hip/hip_runtime.h>
#include <hip/hip_bf16.h>

using sh8   = __attribute__((ext_vector_type(8))) short;
using f32x4 = __attribute__((ext_vector_type(4))) float;

#define DEV __device__ __forceinline__

DEV float leaky(float x) { return x >= 0.f ? x : 0.2f * x; }

DEV unsigned short f2bf(float f) {  // round-to-nearest-even f32 -> bf16 bits
  unsigned u = __float_as_uint(f);
  u += 0x7FFF + ((u >> 16) & 1);
  return (unsigned short)(u >> 16);
}
DEV float bf2f(unsigned short b) { return __uint_as_float(((unsigned)b) << 16); }

// ---------------- weight packing (templated: all dims pow2 -> shifts) ----------------
template<int Cout, int Cin>
DEV void pack7_body(const float* __restrict__ w, unsigned short* __restrict__ wp, int blk) {
  constexpr long plane = (long)(Cin >> 5) * Cout * 32;
  int tid = blk * 256 + threadIdx.x;
  if (tid >= Cout * Cin) return;
  int co = tid / Cin, ci = tid - co * Cin;
  const float* src = w + (long)tid * 7;
  unsigned short* dst = wp + ((long)(ci >> 5) * Cout + co) * 32 + (ci & 31);
  #pragma unroll
  for (int k = 0; k < 7; ++k) dst[k * plane] = f2bf(src[k]);
}
template<int Cout, int Cin>
DEV void packph_body(const float* __restrict__ w, unsigned short* __restrict__ wp, int blk) {
  constexpr long plane = (long)(Cin >> 5) * Cout * 32;
  int tid = blk * 256 + threadIdx.x;
  if (tid >= Cout * Cin) return;
  int co = tid / Cin, ci = tid - co * Cin;
  float wk[7];
  #pragma unroll
  for (int k = 0; k < 7; ++k) wk[k] = w[(long)tid * 7 + k];
  unsigned short* dst = wp + ((long)(ci >> 5) * Cout + co) * 32 + (ci & 31);
  #pragma unroll
  for (int p = 0; p < 4; ++p) {
    #pragma unroll
    for (int d = 0; d < 3; ++d) {
      float s = 0.f;
      #pragma unroll
      for (int k = 0; k < 7; ++k) if (((p + k + 1) >> 2) == d) s += wk[k];
      dst[(p * 3 + d) * plane] = f2bf(s);
    }
  }
}

// ---------------- MLP gemm body (rider blocks inside conv launches) ----------------
// gb in [0,256): jb = gb&31, kc = gb>>5. sum2: h is 2-partial ctx buffer.
DEV void gemm_body(int gb, const float* __restrict__ h, const float* __restrict__ w,
                   float* __restrict__ gpart, int sum2) {
  __shared__ float hl[4][128];
  __shared__ float red[8][4][32];
  const int jb = gb & 31, kc = gb >> 5, k0 = kc * 128;
  for (int i = threadIdx.x; i < 512; i += 256) {
    int bb = i >> 7, kk = i & 127;
    float v;
    if (sum2) {
      int base = ((bb << 10) + k0 + kk) << 1;
      v = h[base] + h[base + 1];
    } else {
      v = h[(bb << 10) + k0 + kk];
    }
    hl[bb][kk] = v;
  }
  __syncthreads();
  const int jl = threadIdx.x & 31, kq = threadIdx.x >> 5;
  const int j = jb * 32 + jl;
  float a0 = 0, a1 = 0, a2 = 0, a3 = 0;
  const float* wp = w + (long)(k0 + kq * 16) * 1024 + j;
  #pragma unroll
  for (int k = 0; k < 16; ++k) {
    float wv = wp[(long)k * 1024];
    a0 += hl[0][kq * 16 + k] * wv;
    a1 += hl[1][kq * 16 + k] * wv;
    a2 += hl[2][kq * 16 + k] * wv;
    a3 += hl[3][kq * 16 + k] * wv;
  }
  red[kq][0][jl] = a0; red[kq][1][jl] = a1; red[kq][2][jl] = a2; red[kq][3][jl] = a3;
  __syncthreads();
  if (threadIdx.x < 128) {
    int bb = threadIdx.x >> 5, j2 = threadIdx.x & 31;
    float s = 0;
    #pragma unroll
    for (int q = 0; q < 8; ++q) s += red[q][bb][j2];
    gpart[((long)kc * 4 + bb) * 1024 + jb * 32 + j2] = s;
  }
}

// ---------------- embed (direct-load MFMA) + pack riders ----------------
// blocks [0,1024): embed 64-row groups. blocks [1024,3744): weight packing.
__global__ __launch_bounds__(256)
void embed_pack(const float* __restrict__ x, const float* __restrict__ ew,
                const float* __restrict__ eb, unsigned short* __restrict__ encbf,
                float* __restrict__ part,
                const float* __restrict__ cw1, const float* __restrict__ cw2,
                const float* __restrict__ cw3, const float* __restrict__ cw4,
                unsigned short* __restrict__ wbuf) {
  if (blockIdx.x >= 1024) {
    int blk = blockIdx.x - 1024;
    if (blk < 2048)      pack7_body<512, 1024>(cw1, wbuf, blk);
    else if (blk < 2560) packph_body<256, 512>(cw2, wbuf + 3670016, blk - 2048);
    else if (blk < 2688) packph_body<128, 256>(cw3, wbuf + 5242880, blk - 2560);
    else                 packph_body<64, 128>(cw4, wbuf + 5636096, blk - 2688);
    return;
  }
  __shared__ unsigned short W16[257 * 16];   // [p][f], f>=8 zeroed
  __shared__ float ctxred[4][8];
  const int tid = threadIdx.x;

  for (int i = tid; i < 257 * 16; i += 256) {
    int p = i >> 4, f = i & 15;
    W16[i] = (f < 8) ? f2bf(ew[p * 8 + f]) : (unsigned short)0;
  }
  __syncthreads();

  const int w = tid >> 6, lane = tid & 63;
  const int m = lane & 15, g = lane >> 4;

  sh8 breg[8];
  #pragma unroll
  for (int kk = 0; kk < 8; ++kk) {
    #pragma unroll
    for (int j = 0; j < 8; ++j)
      breg[kk][j] = (short)W16[(kk * 32 + g * 8 + j) * 16 + m];
  }
  const float w256 = bf2f(W16[256 * 16 + m]);
  const float ebf = (m < 8) ? eb[m] : 0.f;

  const int bid = blockIdx.x;
  const long row0 = (long)bid * 64;
  const int b = bid >> 8, band = (bid >> 1) & 127, half = bid & 1;
  const int t0 = half * 64 + w * 16;

  const float* xp = x + (row0 + w * 16 + m) * 257 + g * 8;
  float vals[8][8];
  #pragma unroll
  for (int kk = 0; kk < 8; ++kk) {
    #pragma unroll
    for (int j = 0; j < 8; ++j)
      vals[kk][j] = xp[kk * 32 + j];
  }
  f32x4 acc = {0.f, 0.f, 0.f, 0.f};
  #pragma unroll
  for (int kk = 0; kk < 8; ++kk) {
    sh8 afr;
    #pragma unroll
    for (int j = 0; j < 8; ++j) afr[j] = (short)f2bf(vals[kk][j]);
    acc = __builtin_amdgcn_mfma_f32_16x16x32_bf16(afr, breg[kk], acc, 0, 0, 0);
  }

  const float* xq = x + (row0 + w * 16 + g * 4) * 257 + 256;
  float ctx_acc = 0.f;
  unsigned short pk[4];
  #pragma unroll
  for (int r = 0; r < 4; ++r) {
    float e = acc[r] + xq[(long)r * 257] * w256 + ebf;
    pk[r] = f2bf(e);
    ctx_acc += e;
  }
  if (m < 8) {
    long o = ((long)b * 1024 + m * 128 + band) * 128 + t0 + g * 4;
    *(ushort4*)(encbf + o) = make_ushort4(pk[0], pk[1], pk[2], pk[3]);
  }

  ctx_acc += __shfl_xor(ctx_acc, 16);
  ctx_acc += __shfl_xor(ctx_acc, 32);
  if (lane < 8) ctxred[w][lane] = ctx_acc;
  __syncthreads();
  if (tid < 8) {
    float sv = ctxred[0][tid] + ctxred[1][tid] + ctxred[2][tid] + ctxred[3][tid];
    part[((b * 1024 + tid * 128 + band) << 1) + half] = sv;
  }
}

// ---------------- implicit-GEMM conv1d (stage 1) + gemm rider ----------------
template<int UPS, int SPLITK>
__global__ __launch_bounds__(256, 2)
void conv_mfma_g(const unsigned short* __restrict__ act,
                 const unsigned short* __restrict__ wpack,
                 float* __restrict__ outp,
                 int Cin, int Cout, int Tout, int nconv,
                 const float* __restrict__ h, const float* __restrict__ wmlp,
                 float* __restrict__ gpart, int sum2) {
  if ((int)blockIdx.x >= nconv) { gemm_body(blockIdx.x - nconv, h, wmlp, gpart, sum2); return; }
  constexpr int NC = (UPS == 1) ? 70 : 18;
  const int Tin = Tout / UPS;
  const int cpb = Cin / SPLITK;
  const int ncib = cpb >> 5;
  const int nCibTot = Cin >> 5;
  const int nco = Cout >> 6, nt = Tout >> 6;

  int bid = blockIdx.x;
  const int sk = bid % SPLITK; bid /= SPLITK;
  const int tt = bid % nt;  bid /= nt;
  const int cot = bid % nco; bid /= nco;
  const int b = bid;
  const int t0 = tt << 6, co0 = cot << 6;
  const int ci0 = sk * cpb;

  extern __shared__ unsigned short lin[];    // [ncib][NC][40]

  const unsigned short* actb = act + ((long)b * Cin + ci0) * Tin;
  const int u_base = (UPS == 1) ? (t0 - 3) : ((t0 >> 2) - 1);
  const int total = cpb * NC;
  for (int i = threadIdx.x; i < total; i += 256) {
    int ci = i / NC, ul = i - ci * NC;
    int u = u_base + ul;
    unsigned short v = 0;
    if (u >= 0 && u < Tin) v = actb[(long)ci * Tin + u];
    lin[((ci >> 5) * NC + ul) * 40 + (ci & 31)] = v;
  }
  __syncthreads();

  const int lane = threadIdx.x & 63, w = threadIdx.x >> 6;
  const int m = lane & 15, g = lane >> 4;

  int boff[28];
  #pragma unroll
  for (int s = 0; s < 4; ++s) {
    #pragma unroll
    for (int k = 0; k < 7; ++k) {
      int row = (UPS == 1) ? (s * 16 + m + k)
                           : (s * 4 + ((m + k + 9) >> 2) - 2);
      boff[s * 7 + k] = row * 40 + g * 8;
    }
  }

  const long wlane = ((long)(co0 + w * 16 + m) * 4 + g) * 8;

  f32x4 acc[4];
  #pragma unroll
  for (int s = 0; s < 4; ++s) { acc[s][0] = 0.f; acc[s][1] = 0.f; acc[s][2] = 0.f; acc[s][3] = 0.f; }

  for (int cib = 0; cib < ncib; ++cib) {
    const unsigned short* lb = lin + cib * (NC * 40);
    const int cg = (ci0 >> 5) + cib;
    sh8 a[7];
    #pragma unroll
    for (int k = 0; k < 7; ++k)
      a[k] = *(const sh8*)(wpack + (long)(k * nCibTot + cg) * Cout * 32 + wlane);
    #pragma unroll
    for (int k = 0; k < 7; ++k) {
      #pragma unroll
      for (int s = 0; s < 4; ++s) {
        sh8 bfr = *(const sh8*)(lb + boff[s * 7 + k]);
        acc[s] = __builtin_amdgcn_mfma_f32_16x16x32_bf16(a[k], bfr, acc[s], 0, 0, 0);
      }
    }
  }

  float* op = outp + (((long)sk * 4 + b) * Cout + (co0 + w * 16 + g * 4)) * (long)Tout + t0 + m;
  #pragma unroll
  for (int r = 0; r < 4; ++r) {
    #pragma unroll
    for (int s = 0; s < 4; ++s)
      op[(long)r * Tout + s * 16] = acc[s][r];
  }
}

// ---------------- phase-decomposed conv + fused bn-apply + gemm rider ----------------
template<int SPLITK>
__global__ __launch_bounds__(256, 2)
void conv_ph_g(const float* __restrict__ csum_in, const float* __restrict__ sp,
               const float* __restrict__ g, const float* __restrict__ be,
               const unsigned short* __restrict__ wpack,
               float* __restrict__ outp,
               int Cin, int Cout, int Tin, int nconv,
               const float* __restrict__ h, const float* __restrict__ wmlp,
               float* __restrict__ gpart, int sum2) {
  if ((int)blockIdx.x >= nconv) { gemm_body(blockIdx.x - nconv, h, wmlp, gpart, sum2); return; }
  const int Tout = Tin << 2;
  const int cpb = Cin / SPLITK;
  const int ncib = cpb >> 5;
  const int nCibTot = Cin >> 5;
  const int nco = Cout >> 6, ntu = Tin >> 6;

  int bid = blockIdx.x;
  const int sk = bid % SPLITK; bid /= SPLITK;
  const int tu = bid % ntu; bid /= ntu;
  const int cot = bid % nco; bid /= nco;
  const int b = bid;
  const int u0 = tu << 6, co0 = cot << 6;
  const int ci0 = sk * cpb;

  extern __shared__ unsigned short lin[];    // [ncib][66][40]
  __shared__ float ssc[64], ssh[64];

  if (threadIdx.x < cpb) {
    int c = ci0 + threadIdx.x;
    float S = sp[c * 4] + sp[c * 4 + 1] + sp[c * 4 + 2] + sp[c * 4 + 3];
    float Q = sp[Cin * 4 + c * 4] + sp[Cin * 4 + c * 4 + 1] + sp[Cin * 4 + c * 4 + 2] + sp[Cin * 4 + c * 4 + 3];
    float n = 4.f * (float)Tin;
    float mean = S / n;
    float var = Q / n - mean * mean;
    float sc = g[c] * rsqrtf(var + 1e-5f);
    ssc[threadIdx.x] = sc;
    ssh[threadIdx.x] = be[c] - mean * sc;
  }
  __syncthreads();

  const float* csb = csum_in + ((long)b * Cin + ci0) * Tin;
  const int total = cpb * 66;
  for (int i = threadIdx.x; i < total; i += 256) {
    int ci = i / 66, r = i - ci * 66;
    int u = u0 - 1 + r;
    unsigned short v = 0;
    if (u >= 0 && u < Tin) {
      float t = csb[(long)ci * Tin + u];
      v = f2bf(leaky(t * ssc[ci] + ssh[ci]));
    }
    lin[((ci >> 5) * 66 + r) * 40 + (ci & 31)] = v;
  }
  __syncthreads();

  const int lane = threadIdx.x & 63, w = threadIdx.x >> 6;
  const int m = lane & 15, g2 = lane >> 4;

  int boff[4][3];
  #pragma unroll
  for (int s = 0; s < 4; ++s)
    #pragma unroll
    for (int d = 0; d < 3; ++d)
      boff[s][d] = (s * 16 + m + d) * 40 + g2 * 8;

  const long wlane = ((long)(co0 + w * 16 + m)) * 32 + g2 * 8;

  f32x4 acc[4][4];                           // [s][p]
  #pragma unroll
  for (int s = 0; s < 4; ++s)
    #pragma unroll
    for (int p = 0; p < 4; ++p) { acc[s][p][0] = 0.f; acc[s][p][1] = 0.f; acc[s][p][2] = 0.f; acc[s][p][3] = 0.f; }

  for (int cib = 0; cib < ncib; ++cib) {
    const unsigned short* lb = lin + cib * (66 * 40);
    const int cg = (ci0 >> 5) + cib;
    sh8 a[12];
    #pragma unroll
    for (int pd = 0; pd < 12; ++pd)
      a[pd] = *(const sh8*)(wpack + ((long)(pd * nCibTot + cg) * Cout) * 32 + wlane);
    #pragma unroll
    for (int s = 0; s < 4; ++s) {
      sh8 b0 = *(const sh8*)(lb + boff[s][0]);
      sh8 b1 = *(const sh8*)(lb + boff[s][1]);
      sh8 b2 = *(const sh8*)(lb + boff[s][2]);
      acc[s][0] = __builtin_amdgcn_mfma_f32_16x16x32_bf16(a[0],  b0, acc[s][0], 0, 0, 0);
      acc[s][0] = __builtin_amdgcn_mfma_f32_16x16x32_bf16(a[1],  b1, acc[s][0], 0, 0, 0);
      acc[s][1] = __builtin_amdgcn_mfma_f32_16x16x32_bf16(a[3],  b0, acc[s][1], 0, 0, 0);
      acc[s][1] = __builtin_amdgcn_mfma_f32_16x16x32_bf16(a[4],  b1, acc[s][1], 0, 0, 0);
      acc[s][1] = __builtin_amdgcn_mfma_f32_16x16x32_bf16(a[5],  b2, acc[s][1], 0, 0, 0);
      acc[s][2] = __builtin_amdgcn_mfma_f32_16x16x32_bf16(a[6],  b0, acc[s][2], 0, 0, 0);
      acc[s][2] = __builtin_amdgcn_mfma_f32_16x16x32_bf16(a[7],  b1, acc[s][2], 0, 0, 0);
      acc[s][2] = __builtin_amdgcn_mfma_f32_16x16x32_bf16(a[8],  b2, acc[s][2], 0, 0, 0);
      acc[s][3] = __builtin_amdgcn_mfma_f32_16x16x32_bf16(a[10], b1, acc[s][3], 0, 0, 0);
      acc[s][3] = __builtin_amdgcn_mfma_f32_16x16x32_bf16(a[11], b2, acc[s][3], 0, 0, 0);
    }
  }

  float* op = outp + (((long)sk * 4 + b) * Cout + (co0 + w * 16 + g2 * 4)) * (long)Tout;
  #pragma unroll
  for (int r = 0; r < 4; ++r) {
    #pragma unroll
    for (int s = 0; s < 4; ++s) {
      float4 v4 = make_float4(acc[s][0][r], acc[s][1][r], acc[s][2][r], acc[s][3][r]);
      *(float4*)(op + (long)r * Tout + ((u0 + s * 16 + m) << 2)) = v4;
    }
  }
}

// ---------------- bn stats (1D grid) + lnsum / fin riders ----------------
// blocks [0, C*4): bnsum (c=blk>>2, b=blk&3).
// mode 1: +4 blocks lnsum. mode 2: +16 blocks fin. mode 0: none.
__global__ __launch_bounds__(256)
void bnsum_ln(const float* __restrict__ p, float* __restrict__ sp,
              float* __restrict__ csum, int C, int T, int SK, int mode,
              const float* __restrict__ gpart, const float* __restrict__ bias,
              const float* __restrict__ g, const float* __restrict__ be,
              float* __restrict__ outp) {
  const int nbn = C * 4;
  if ((int)blockIdx.x >= nbn) {
    if (mode == 1) {
      // lnsum: sum split-K partials + bias + leaky + layernorm
      int b = blockIdx.x - nbn;
      __shared__ float buf[1024];
      __shared__ float rs2[4], rq2[4];
      float s = 0, q = 0;
      #pragma unroll
      for (int i = 0; i < 4; ++i) {
        int j = threadIdx.x + i * 256;
        float v = bias[j];
        #pragma unroll
        for (int kc = 0; kc < 8; ++kc) v += gpart[((long)kc * 4 + b) * 1024 + j];
        v = leaky(v);
        buf[j] = v; s += v; q += v * v;
      }
      #pragma unroll
      for (int off = 32; off; off >>= 1) { s += __shfl_down(s, off); q += __shfl_down(q, off); }
      int wid = threadIdx.x >> 6, lane = threadIdx.x & 63;
      if (lane == 0) { rs2[wid] = s; rq2[wid] = q; }
      __syncthreads();
      float S = rs2[0] + rs2[1] + rs2[2] + rs2[3];
      float Q = rq2[0] + rq2[1] + rq2[2] + rq2[3];
      float mean = S * (1.f / 1024.f);
      float var = Q * (1.f / 1024.f) - mean * mean;
      float rstd = rsqrtf(var + 1e-5f);
      #pragma unroll
      for (int i = 0; i < 4; ++i) {
        int j = threadIdx.x + i * 256;
        outp[b * 1024 + j] = (buf[j] - mean) * rstd * g[j] + be[j];
      }
    } else {
      // fin: ctx_out = sum partials + bias
      int i = (blockIdx.x - nbn) * 256 + threadIdx.x;
      int b = i >> 10, j = i & 1023;
      float v = bias[j];
      #pragma unroll
      for (int kc = 0; kc < 8; ++kc) v += gpart[((long)kc * 4 + b) * 1024 + j];
      outp[i] = v;
    }
    return;
  }
  const int c = blockIdx.x >> 2, b = blockIdx.x & 3;
  long stride = (long)4 * C * T;
  const float* r = p + ((long)b * C + c) * T;
  float* cw = csum + ((long)b * C + c) * T;
  float s = 0, q = 0;
  for (int t = threadIdx.x; t < T; t += 256) {
    float v = r[t];
    for (int k = 1; k < SK; ++k) v += r[t + k * stride];
    cw[t] = v;
    s += v; q += v * v;
  }
  #pragma unroll
  for (int off = 32; off; off >>= 1) { s += __shfl_down(s, off); q += __shfl_down(q, off); }
  __shared__ float rs[4], rq[4];
  int wid = threadIdx.x >> 6, lane = threadIdx.x & 63;
  if (lane == 0) { rs[wid] = s; rq[wid] = q; }
  __syncthreads();
  if (threadIdx.x == 0) {
    sp[c * 4 + b] = rs[0] + rs[1] + rs[2] + rs[3];
    sp[C * 4 + c * 4 + b] = rq[0] + rq[1] + rq[2] + rq[3];
  }
}

// ---------------- final conv: phase-decomposed 3-tap, FUSED bn-apply staging ----------------
__global__ __launch_bounds__(256)
void conv5_kernel(const float* __restrict__ csum_in, const float* __restrict__ sp,
                  const float* __restrict__ g, const float* __restrict__ be,
                  const float* __restrict__ wgt, const float* __restrict__ bias,
                  float* __restrict__ out, int Tout) {
  __shared__ unsigned short sv[64 * 66];
  __shared__ float wph[64 * 13];
  __shared__ float ssc[64], ssh[64];

  const int b = blockIdx.y;
  const int u0 = blockIdx.x * 64;
  const int Tin = Tout >> 2;
  const int tid = threadIdx.x;

  {
    int ci = tid >> 2, pp = tid & 3;
    float s0 = 0, s1 = 0, s2 = 0;
    #pragma unroll
    for (int k = 0; k < 7; ++k) {
      int d = (pp - 3 + k + 4) >> 2;
      float wv = wgt[ci * 7 + k];
      if (d == 0) s0 += wv; else if (d == 1) s1 += wv; else s2 += wv;
    }
    wph[ci * 13 + pp * 3 + 0] = s0;
    wph[ci * 13 + pp * 3 + 1] = s1;
    wph[ci * 13 + pp * 3 + 2] = s2;
  }
  if (tid < 64) {
    float S = sp[tid * 4] + sp[tid * 4 + 1] + sp[tid * 4 + 2] + sp[tid * 4 + 3];
    float Q = sp[256 + tid * 4] + sp[256 + tid * 4 + 1] + sp[256 + tid * 4 + 2] + sp[256 + tid * 4 + 3];
    float n = 4.f * (float)Tin;
    float mean = S / n;
    float var = Q / n - mean * mean;
    float sc = g[tid] * rsqrtf(var + 1e-5f);
    ssc[tid] = sc;
    ssh[tid] = be[tid] - mean * sc;
  }
  __syncthreads();

  const float* inb = csum_in + (long)b * 64 * Tin;
  for (int i = tid; i < 64 * 66; i += 256) {
    int ci = i / 66, uu = i - ci * 66;
    int u = u0 - 1 + uu;
    unsigned short v = 0;
    if (u >= 0 && u < Tin) {
      float t = inb[(long)ci * Tin + u];
      v = f2bf(leaky(t * ssc[ci] + ssh[ci]));
    }
    sv[ci * 66 + uu] = v;
  }
  __syncthreads();

  const int ul = tid >> 2;
  const int chunk = tid & 3;
  float a0 = 0, a1 = 0, a2 = 0, a3 = 0;
  #pragma unroll
  for (int cc = 0; cc < 16; ++cc) {
    int ci = chunk * 16 + cc;
    float v0 = bf2f(sv[ci * 66 + ul]);
    float v1 = bf2f(sv[ci * 66 + ul + 1]);
    float v2 = bf2f(sv[ci * 66 + ul + 2]);
    const float* wp = wph + ci * 13;
    a0 += v0 * wp[0] + v1 * wp[1];
    a1 += v0 * wp[3] + v1 * wp[4] + v2 * wp[5];
    a2 += v0 * wp[6] + v1 * wp[7] + v2 * wp[8];
    a3 += v1 * wp[10] + v2 * wp[11];
  }
  #pragma unroll
  for (int msk = 1; msk <= 2; msk <<= 1) {
    a0 += __shfl_xor(a0, msk);
    a1 += __shfl_xor(a1, msk);
    a2 += __shfl_xor(a2, msk);
    a3 += __shfl_xor(a3, msk);
  }
  if (chunk == 0) {
    float bv = bias[0];
    float4 r = make_float4(a0 + bv, a1 + bv, a2 + bv, a3 + bv);
    *(float4*)(out + (long)b * Tout + (long)(u0 + ul) * 4) = r;
  }
}

extern "C" void kernel_launch(void* const* d_in, const int* in_sizes, int n_in,
                              void* d_out, int out_size, void* d_ws, size_t ws_size,
                              hipStream_t stream) {
  const float* x     = (const float*)d_in[0];
  // d_in[1] = atoms: dead (sparse_code result unused by outputs)
  const float* ew    = (const float*)d_in[2];
  const float* eb    = (const float*)d_in[3];
  const float* w1    = (const float*)d_in[4];
  const float* b1    = (const float*)d_in[5];
  const float* g1    = (const float*)d_in[6];
  const float* be1   = (const float*)d_in[7];
  const float* w2    = (const float*)d_in[8];
  const float* b2    = (const float*)d_in[9];
  const float* g2    = (const float*)d_in[10];
  const float* be2   = (const float*)d_in[11];
  const float* w3    = (const float*)d_in[12];
  const float* b3    = (const float*)d_in[13];
  const float* up_w1 = (const float*)d_in[14];
  const float* up_b1 = (const float*)d_in[15];
  const float* bn_g1 = (const float*)d_in[16];
  const float* bn_b1 = (const float*)d_in[17];
  const float* up_w2 = (const float*)d_in[18];
  const float* up_b2 = (const float*)d_in[19];
  const float* bn_g2 = (const float*)d_in[20];
  const float* bn_b2 = (const float*)d_in[21];
  const float* up_w3 = (const float*)d_in[22];
  const float* up_b3 = (const float*)d_in[23];
  const float* bn_g3 = (const float*)d_in[24];
  const float* bn_b3 = (const float*)d_in[25];
  const float* up_w4 = (const float*)d_in[26];
  const float* up_b4 = (const float*)d_in[27];
  const float* bn_g4 = (const float*)d_in[28];
  const float* bn_b4 = (const float*)d_in[29];
  const float* up_w5 = (const float*)d_in[30];
  const float* up_b5 = (const float*)d_in[31];

  float* out = (float*)d_out;              // [0,131072) = y, [131072,135168) = ctx_out

  float* ws = (float*)d_ws;
  float* part   = ws;                      // 8192
  float* gpart  = part + 8192;             // 32768
  float* t2     = gpart + 32768;           // 4096
  float* statsp = t2 + 4096;               // 4096
  float* csum   = statsp + 4096;           // 2097152
  float* pbuf   = csum + 2097152;          // 4194304
  unsigned short* encbf = (unsigned short*)(pbuf + 4194304);  // 524288 u16
  unsigned short* wbuf  = encbf + 524288;  // 5734400 u16

  // 1: embed (direct-load MFMA, fused ctx partials) + weight packing riders
  embed_pack<<<3744, 256, 0, stream>>>(x, ew, eb, encbf, part,
                                       up_w1, up_w2, up_w3, up_w4, wbuf);

  // 2: conv stage 1 + MLP gemm1 rider (reads part from launch 1)
  conv_mfma_g<1, 8><<<768, 256, 22400, stream>>>(encbf, wbuf, pbuf, 1024, 512, 128,
                                                 512, part, w1, gpart, 1);
  // 3: bnsum1 + lnsum1 rider (gpart -> t2)
  bnsum_ln<<<2052, 256, 0, stream>>>(pbuf, statsp, csum, 512, 128, 8, 1,
                                     gpart, b1, g1, be1, t2);
  // 4: conv stage 2 + gemm2 rider (t2 -> gpart)
  conv_ph_g<8><<<512, 256, 10560, stream>>>(csum, statsp, bn_g1, bn_b1, wbuf + 3670016,
                                            pbuf, 512, 256, 128,
                                            256, t2, w2, gpart, 0);
  // 5: bnsum2 + lnsum2 rider (gpart -> t2)
  bnsum_ln<<<1028, 256, 0, stream>>>(pbuf, statsp, csum, 256, 512, 8, 1,
                                     gpart, b2, g2, be2, t2);
  // 6: conv stage 3 + gemm3 rider (t2 -> gpart)
  conv_ph_g<4><<<512, 256, 10560, stream>>>(csum, statsp, bn_g2, bn_b2, wbuf + 5242880,
                                            pbuf, 256, 128, 512,
                                            256, t2, w3, gpart, 0);
  // 7: bnsum3 + fin rider (gpart -> ctx_out)
  bnsum_ln<<<528, 256, 0, stream>>>(pbuf, statsp, csum, 128, 2048, 4, 2,
                                    gpart, b3, b3, b3, out + 131072);
  // 8: conv stage 4 (no rider)
  conv_ph_g<2><<<256, 256, 10560, stream>>>(csum, statsp, bn_g3, bn_b3, wbuf + 5636096,
                                            pbuf, 128, 64, 2048,
                                            256, t2, w3, gpart, -1);
  // 9: bnsum4
  bnsum_ln<<<256, 256, 0, stream>>>(pbuf, statsp, csum, 64, 8192, 2, 0,
                                    gpart, b3, b3, b3, out + 131072);
  // 10: conv stage 5
  conv5_kernel<<<dim3(128, 4), 256, 0, stream>>>(csum, statsp, bn_g4, bn_b4, up_w5, up_b5, out, 32768);
}

// Round 13
// 139.358 us; speedup vs baseline: 1.2093x; 1.0588x over previous
//
#include <hip/hip_runtime.h>
#include <hip/hip_bf16.h>

using sh8   = __attribute__((ext_vector_type(8))) short;
using f32x4 = __attribute__((ext_vector_type(4))) float;

#define DEV __device__ __forceinline__

DEV float leaky(float x) { return x >= 0.f ? x : 0.2f * x; }

DEV unsigned short f2bf(float f) {  // round-to-nearest-even f32 -> bf16 bits
  unsigned u = __float_as_uint(f);
  u += 0x7FFF + ((u >> 16) & 1);
  return (unsigned short)(u >> 16);
}
DEV float bf2f(unsigned short b) { return __uint_as_float(((unsigned)b) << 16); }

// ---------------- weight packing (templated: all dims pow2 -> shifts) ----------------
template<int Cout, int Cin>
DEV void pack7_body(const float* __restrict__ w, unsigned short* __restrict__ wp, int blk) {
  constexpr long plane = (long)(Cin >> 5) * Cout * 32;
  int tid = blk * 256 + threadIdx.x;
  if (tid >= Cout * Cin) return;
  int co = tid / Cin, ci = tid - co * Cin;
  const float* src = w + (long)tid * 7;
  unsigned short* dst = wp + ((long)(ci >> 5) * Cout + co) * 32 + (ci & 31);
  #pragma unroll
  for (int k = 0; k < 7; ++k) dst[k * plane] = f2bf(src[k]);
}
template<int Cout, int Cin>
DEV void packph_body(const float* __restrict__ w, unsigned short* __restrict__ wp, int blk) {
  constexpr long plane = (long)(Cin >> 5) * Cout * 32;
  int tid = blk * 256 + threadIdx.x;
  if (tid >= Cout * Cin) return;
  int co = tid / Cin, ci = tid - co * Cin;
  float wk[7];
  #pragma unroll
  for (int k = 0; k < 7; ++k) wk[k] = w[(long)tid * 7 + k];
  unsigned short* dst = wp + ((long)(ci >> 5) * Cout + co) * 32 + (ci & 31);
  #pragma unroll
  for (int p = 0; p < 4; ++p) {
    #pragma unroll
    for (int d = 0; d < 3; ++d) {
      float s = 0.f;
      #pragma unroll
      for (int k = 0; k < 7; ++k) if (((p + k + 1) >> 2) == d) s += wk[k];
      dst[(p * 3 + d) * plane] = f2bf(s);
    }
  }
}

// ---------------- MLP gemm body (rider blocks inside conv launches) ----------------
DEV void gemm_body(int gb, const float* __restrict__ h, const float* __restrict__ w,
                   float* __restrict__ gpart, int sum2) {
  __shared__ float hl[4][128];
  __shared__ float red[8][4][32];
  const int jb = gb & 31, kc = gb >> 5, k0 = kc * 128;
  for (int i = threadIdx.x; i < 512; i += 256) {
    int bb = i >> 7, kk = i & 127;
    float v;
    if (sum2) {
      int base = ((bb << 10) + k0 + kk) << 1;
      v = h[base] + h[base + 1];
    } else {
      v = h[(bb << 10) + k0 + kk];
    }
    hl[bb][kk] = v;
  }
  __syncthreads();
  const int jl = threadIdx.x & 31, kq = threadIdx.x >> 5;
  const int j = jb * 32 + jl;
  float a0 = 0, a1 = 0, a2 = 0, a3 = 0;
  const float* wp = w + (long)(k0 + kq * 16) * 1024 + j;
  #pragma unroll
  for (int k = 0; k < 16; ++k) {
    float wv = wp[(long)k * 1024];
    a0 += hl[0][kq * 16 + k] * wv;
    a1 += hl[1][kq * 16 + k] * wv;
    a2 += hl[2][kq * 16 + k] * wv;
    a3 += hl[3][kq * 16 + k] * wv;
  }
  red[kq][0][jl] = a0; red[kq][1][jl] = a1; red[kq][2][jl] = a2; red[kq][3][jl] = a3;
  __syncthreads();
  if (threadIdx.x < 128) {
    int bb = threadIdx.x >> 5, j2 = threadIdx.x & 31;
    float s = 0;
    #pragma unroll
    for (int q = 0; q < 8; ++q) s += red[q][bb][j2];
    gpart[((long)kc * 4 + bb) * 1024 + jb * 32 + j2] = s;
  }
}

// ---------------- embed (direct-load MFMA) + pack riders ----------------
__global__ __launch_bounds__(256)
void embed_pack(const float* __restrict__ x, const float* __restrict__ ew,
                const float* __restrict__ eb, unsigned short* __restrict__ encbf,
                float* __restrict__ part,
                const float* __restrict__ cw1, const float* __restrict__ cw2,
                const float* __restrict__ cw3, const float* __restrict__ cw4,
                unsigned short* __restrict__ wbuf) {
  if (blockIdx.x >= 1024) {
    int blk = blockIdx.x - 1024;
    if (blk < 2048)      pack7_body<512, 1024>(cw1, wbuf, blk);
    else if (blk < 2560) packph_body<256, 512>(cw2, wbuf + 3670016, blk - 2048);
    else if (blk < 2688) packph_body<128, 256>(cw3, wbuf + 5242880, blk - 2560);
    else                 packph_body<64, 128>(cw4, wbuf + 5636096, blk - 2688);
    return;
  }
  __shared__ unsigned short W16[257 * 16];   // [p][f], f>=8 zeroed
  __shared__ float ctxred[4][8];
  const int tid = threadIdx.x;

  for (int i = tid; i < 257 * 16; i += 256) {
    int p = i >> 4, f = i & 15;
    W16[i] = (f < 8) ? f2bf(ew[p * 8 + f]) : (unsigned short)0;
  }
  __syncthreads();

  const int w = tid >> 6, lane = tid & 63;
  const int m = lane & 15, g = lane >> 4;

  sh8 breg[8];
  #pragma unroll
  for (int kk = 0; kk < 8; ++kk) {
    #pragma unroll
    for (int j = 0; j < 8; ++j)
      breg[kk][j] = (short)W16[(kk * 32 + g * 8 + j) * 16 + m];
  }
  const float w256 = bf2f(W16[256 * 16 + m]);
  const float ebf = (m < 8) ? eb[m] : 0.f;

  const int bid = blockIdx.x;
  const long row0 = (long)bid * 64;
  const int b = bid >> 8, band = (bid >> 1) & 127, half = bid & 1;
  const int t0 = half * 64 + w * 16;

  const float* xp = x + (row0 + w * 16 + m) * 257 + g * 8;
  float vals[8][8];
  #pragma unroll
  for (int kk = 0; kk < 8; ++kk) {
    #pragma unroll
    for (int j = 0; j < 8; ++j)
      vals[kk][j] = xp[kk * 32 + j];
  }
  f32x4 acc = {0.f, 0.f, 0.f, 0.f};
  #pragma unroll
  for (int kk = 0; kk < 8; ++kk) {
    sh8 afr;
    #pragma unroll
    for (int j = 0; j < 8; ++j) afr[j] = (short)f2bf(vals[kk][j]);
    acc = __builtin_amdgcn_mfma_f32_16x16x32_bf16(afr, breg[kk], acc, 0, 0, 0);
  }

  const float* xq = x + (row0 + w * 16 + g * 4) * 257 + 256;
  float ctx_acc = 0.f;
  unsigned short pk[4];
  #pragma unroll
  for (int r = 0; r < 4; ++r) {
    float e = acc[r] + xq[(long)r * 257] * w256 + ebf;
    pk[r] = f2bf(e);
    ctx_acc += e;
  }
  if (m < 8) {
    long o = ((long)b * 1024 + m * 128 + band) * 128 + t0 + g * 4;
    *(ushort4*)(encbf + o) = make_ushort4(pk[0], pk[1], pk[2], pk[3]);
  }

  ctx_acc += __shfl_xor(ctx_acc, 16);
  ctx_acc += __shfl_xor(ctx_acc, 32);
  if (lane < 8) ctxred[w][lane] = ctx_acc;
  __syncthreads();
  if (tid < 8) {
    float sv = ctxred[0][tid] + ctxred[1][tid] + ctxred[2][tid] + ctxred[3][tid];
    part[((b * 1024 + tid * 128 + band) << 1) + half] = sv;
  }
}

// ---------------- conv stage 1 (UPS=1, 32-t tiles) + gemm rider ----------------
// Cin=1024, Cout=512, Tout=128 fixed. NC = 32+6 = 38.
template<int SPLITK>
__global__ __launch_bounds__(256, 2)
void conv1_g(const unsigned short* __restrict__ act,
             const unsigned short* __restrict__ wpack,
             float* __restrict__ outp, int nconv,
             const float* __restrict__ h, const float* __restrict__ wmlp,
             float* __restrict__ gpart, int sum2) {
  if ((int)blockIdx.x >= nconv) { gemm_body(blockIdx.x - nconv, h, wmlp, gpart, sum2); return; }
  constexpr int Cin = 1024, Cout = 512, Tout = 128, Tin = 128, NC = 38;
  constexpr int cpb = Cin / SPLITK;
  constexpr int ncib = cpb >> 5;
  constexpr int nCibTot = Cin >> 5;

  int bid = blockIdx.x;
  const int sk = bid % SPLITK; bid /= SPLITK;
  const int tt = bid & 3;  bid >>= 2;        // nt = 4 (32-t tiles)
  const int cot = bid & 7; bid >>= 3;        // nco = 8
  const int b = bid;
  const int t0 = tt << 5, co0 = cot << 6;
  const int ci0 = sk * cpb;

  extern __shared__ unsigned short lin[];    // [ncib][NC][40]

  const unsigned short* actb = act + ((long)b * Cin + ci0) * Tin;
  const int u_base = t0 - 3;
  const int total = cpb * NC;
  for (int i = threadIdx.x; i < total; i += 256) {
    int ci = i / NC, ul = i - ci * NC;
    int u = u_base + ul;
    unsigned short v = 0;
    if (u >= 0 && u < Tin) v = actb[(long)ci * Tin + u];
    lin[((ci >> 5) * NC + ul) * 40 + (ci & 31)] = v;
  }
  __syncthreads();

  const int lane = threadIdx.x & 63, w = threadIdx.x >> 6;
  const int m = lane & 15, g = lane >> 4;

  int boff[2][7];
  #pragma unroll
  for (int s = 0; s < 2; ++s)
    #pragma unroll
    for (int k = 0; k < 7; ++k)
      boff[s][k] = (s * 16 + m + k) * 40 + g * 8;

  const long wlane = ((long)(co0 + w * 16 + m) * 4 + g) * 8;

  f32x4 acc[2];
  #pragma unroll
  for (int s = 0; s < 2; ++s) { acc[s][0] = 0.f; acc[s][1] = 0.f; acc[s][2] = 0.f; acc[s][3] = 0.f; }

  for (int cib = 0; cib < ncib; ++cib) {
    const unsigned short* lb = lin + cib * (NC * 40);
    const int cg = (ci0 >> 5) + cib;
    sh8 a[7];
    #pragma unroll
    for (int k = 0; k < 7; ++k)
      a[k] = *(const sh8*)(wpack + (long)(k * nCibTot + cg) * Cout * 32 + wlane);
    #pragma unroll
    for (int k = 0; k < 7; ++k) {
      #pragma unroll
      for (int s = 0; s < 2; ++s) {
        sh8 bfr = *(const sh8*)(lb + boff[s][k]);
        acc[s] = __builtin_amdgcn_mfma_f32_16x16x32_bf16(a[k], bfr, acc[s], 0, 0, 0);
      }
    }
  }

  float* op = outp + (((long)sk * 4 + b) * Cout + (co0 + w * 16 + g * 4)) * (long)Tout + t0 + m;
  #pragma unroll
  for (int r = 0; r < 4; ++r) {
    #pragma unroll
    for (int s = 0; s < 2; ++s)
      op[(long)r * Tout + s * 16] = acc[s][r];
  }
}

// ---------------- phase-decomposed conv (32-u tiles) + fused bn-apply + gemm rider ----------------
// NC = 32+2 = 34. ssc/ssh sized for cpb<=128.
template<int SPLITK>
__global__ __launch_bounds__(256, 2)
void conv_ph_g(const float* __restrict__ csum_in, const float* __restrict__ sp,
               const float* __restrict__ g, const float* __restrict__ be,
               const unsigned short* __restrict__ wpack,
               float* __restrict__ outp,
               int Cin, int Cout, int Tin, int nconv,
               const float* __restrict__ h, const float* __restrict__ wmlp,
               float* __restrict__ gpart, int sum2) {
  if ((int)blockIdx.x >= nconv) { gemm_body(blockIdx.x - nconv, h, wmlp, gpart, sum2); return; }
  constexpr int NC = 34;
  const int Tout = Tin << 2;
  const int cpb = Cin / SPLITK;
  const int ncib = cpb >> 5;
  const int nCibTot = Cin >> 5;
  const int nco = Cout >> 6, ntu = Tin >> 5;

  int bid = blockIdx.x;
  const int sk = bid % SPLITK; bid /= SPLITK;
  const int tu = bid % ntu; bid /= ntu;
  const int cot = bid % nco; bid /= nco;
  const int b = bid;
  const int u0 = tu << 5, co0 = cot << 6;
  const int ci0 = sk * cpb;

  extern __shared__ unsigned short lin[];    // [ncib][NC][40]
  __shared__ float ssc[128], ssh[128];

  if (threadIdx.x < cpb) {
    int c = ci0 + threadIdx.x;
    float S = sp[c * 4] + sp[c * 4 + 1] + sp[c * 4 + 2] + sp[c * 4 + 3];
    float Q = sp[Cin * 4 + c * 4] + sp[Cin * 4 + c * 4 + 1] + sp[Cin * 4 + c * 4 + 2] + sp[Cin * 4 + c * 4 + 3];
    float n = 4.f * (float)Tin;
    float mean = S / n;
    float var = Q / n - mean * mean;
    float sc = g[c] * rsqrtf(var + 1e-5f);
    ssc[threadIdx.x] = sc;
    ssh[threadIdx.x] = be[c] - mean * sc;
  }
  __syncthreads();

  const float* csb = csum_in + ((long)b * Cin + ci0) * Tin;
  const int total = cpb * NC;
  for (int i = threadIdx.x; i < total; i += 256) {
    int ci = i / NC, r = i - ci * NC;
    int u = u0 - 1 + r;
    unsigned short v = 0;
    if (u >= 0 && u < Tin) {
      float t = csb[(long)ci * Tin + u];
      v = f2bf(leaky(t * ssc[ci] + ssh[ci]));
    }
    lin[((ci >> 5) * NC + r) * 40 + (ci & 31)] = v;
  }
  __syncthreads();

  const int lane = threadIdx.x & 63, w = threadIdx.x >> 6;
  const int m = lane & 15, g2 = lane >> 4;

  int boff[2][3];
  #pragma unroll
  for (int s = 0; s < 2; ++s)
    #pragma unroll
    for (int d = 0; d < 3; ++d)
      boff[s][d] = (s * 16 + m + d) * 40 + g2 * 8;

  const long wlane = ((long)(co0 + w * 16 + m)) * 32 + g2 * 8;

  f32x4 acc[2][4];                           // [s][p]
  #pragma unroll
  for (int s = 0; s < 2; ++s)
    #pragma unroll
    for (int p = 0; p < 4; ++p) { acc[s][p][0] = 0.f; acc[s][p][1] = 0.f; acc[s][p][2] = 0.f; acc[s][p][3] = 0.f; }

  for (int cib = 0; cib < ncib; ++cib) {
    const unsigned short* lb = lin + cib * (NC * 40);
    const int cg = (ci0 >> 5) + cib;
    sh8 a[12];
    #pragma unroll
    for (int pd = 0; pd < 12; ++pd)
      a[pd] = *(const sh8*)(wpack + ((long)(pd * nCibTot + cg) * Cout) * 32 + wlane);
    #pragma unroll
    for (int s = 0; s < 2; ++s) {
      sh8 b0 = *(const sh8*)(lb + boff[s][0]);
      sh8 b1 = *(const sh8*)(lb + boff[s][1]);
      sh8 b2 = *(const sh8*)(lb + boff[s][2]);
      acc[s][0] = __builtin_amdgcn_mfma_f32_16x16x32_bf16(a[0],  b0, acc[s][0], 0, 0, 0);
      acc[s][0] = __builtin_amdgcn_mfma_f32_16x16x32_bf16(a[1],  b1, acc[s][0], 0, 0, 0);
      acc[s][1] = __builtin_amdgcn_mfma_f32_16x16x32_bf16(a[3],  b0, acc[s][1], 0, 0, 0);
      acc[s][1] = __builtin_amdgcn_mfma_f32_16x16x32_bf16(a[4],  b1, acc[s][1], 0, 0, 0);
      acc[s][1] = __builtin_amdgcn_mfma_f32_16x16x32_bf16(a[5],  b2, acc[s][1], 0, 0, 0);
      acc[s][2] = __builtin_amdgcn_mfma_f32_16x16x32_bf16(a[6],  b0, acc[s][2], 0, 0, 0);
      acc[s][2] = __builtin_amdgcn_mfma_f32_16x16x32_bf16(a[7],  b1, acc[s][2], 0, 0, 0);
      acc[s][2] = __builtin_amdgcn_mfma_f32_16x16x32_bf16(a[8],  b2, acc[s][2], 0, 0, 0);
      acc[s][3] = __builtin_amdgcn_mfma_f32_16x16x32_bf16(a[10], b1, acc[s][3], 0, 0, 0);
      acc[s][3] = __builtin_amdgcn_mfma_f32_16x16x32_bf16(a[11], b2, acc[s][3], 0, 0, 0);
    }
  }

  float* op = outp + (((long)sk * 4 + b) * Cout + (co0 + w * 16 + g2 * 4)) * (long)Tout;
  #pragma unroll
  for (int r = 0; r < 4; ++r) {
    #pragma unroll
    for (int s = 0; s < 2; ++s) {
      float4 v4 = make_float4(acc[s][0][r], acc[s][1][r], acc[s][2][r], acc[s][3][r]);
      *(float4*)(op + (long)r * Tout + ((u0 + s * 16 + m) << 2)) = v4;
    }
  }
}

// ---------------- bn stats (1D grid) + lnsum / fin riders ----------------
// blocks [0, C*4): bnsum. mode 1: +4 lnsum blocks. mode 2: +16 fin blocks.
// docopy=0: stats only (no csum write; SK must be 1).
__global__ __launch_bounds__(256)
void bnsum_ln(const float* __restrict__ p, float* __restrict__ sp,
              float* __restrict__ csum, int C, int T, int SK, int docopy, int mode,
              const float* __restrict__ gpart, const float* __restrict__ bias,
              const float* __restrict__ g, const float* __restrict__ be,
              float* __restrict__ outp) {
  const int nbn = C * 4;
  if ((int)blockIdx.x >= nbn) {
    if (mode == 1) {
      int b = blockIdx.x - nbn;
      __shared__ float buf[1024];
      __shared__ float rs2[4], rq2[4];
      float s = 0, q = 0;
      #pragma unroll
      for (int i = 0; i < 4; ++i) {
        int j = threadIdx.x + i * 256;
        float v = bias[j];
        #pragma unroll
        for (int kc = 0; kc < 8; ++kc) v += gpart[((long)kc * 4 + b) * 1024 + j];
        v = leaky(v);
        buf[j] = v; s += v; q += v * v;
      }
      #pragma unroll
      for (int off = 32; off; off >>= 1) { s += __shfl_down(s, off); q += __shfl_down(q, off); }
      int wid = threadIdx.x >> 6, lane = threadIdx.x & 63;
      if (lane == 0) { rs2[wid] = s; rq2[wid] = q; }
      __syncthreads();
      float S = rs2[0] + rs2[1] + rs2[2] + rs2[3];
      float Q = rq2[0] + rq2[1] + rq2[2] + rq2[3];
      float mean = S * (1.f / 1024.f);
      float var = Q * (1.f / 1024.f) - mean * mean;
      float rstd = rsqrtf(var + 1e-5f);
      #pragma unroll
      for (int i = 0; i < 4; ++i) {
        int j = threadIdx.x + i * 256;
        outp[b * 1024 + j] = (buf[j] - mean) * rstd * g[j] + be[j];
      }
    } else {
      int i = (blockIdx.x - nbn) * 256 + threadIdx.x;
      int b = i >> 10, j = i & 1023;
      float v = bias[j];
      #pragma unroll
      for (int kc = 0; kc < 8; ++kc) v += gpart[((long)kc * 4 + b) * 1024 + j];
      outp[i] = v;
    }
    return;
  }
  const int c = blockIdx.x >> 2, b = blockIdx.x & 3;
  long stride = (long)4 * C * T;
  const float* r = p + ((long)b * C + c) * T;
  float* cw = csum + ((long)b * C + c) * T;
  float s = 0, q = 0;
  for (int t = threadIdx.x; t < T; t += 256) {
    float v = r[t];
    for (int k = 1; k < SK; ++k) v += r[t + k * stride];
    if (docopy) cw[t] = v;
    s += v; q += v * v;
  }
  #pragma unroll
  for (int off = 32; off; off >>= 1) { s += __shfl_down(s, off); q += __shfl_down(q, off); }
  __shared__ float rs[4], rq[4];
  int wid = threadIdx.x >> 6, lane = threadIdx.x & 63;
  if (lane == 0) { rs[wid] = s; rq[wid] = q; }
  __syncthreads();
  if (threadIdx.x == 0) {
    sp[c * 4 + b] = rs[0] + rs[1] + rs[2] + rs[3];
    sp[C * 4 + c * 4 + b] = rq[0] + rq[1] + rq[2] + rq[3];
  }
}

// ---------------- final conv: phase-decomposed 3-tap, FUSED bn-apply staging ----------------
__global__ __launch_bounds__(256)
void conv5_kernel(const float* __restrict__ csum_in, const float* __restrict__ sp,
                  const float* __restrict__ g, const float* __restrict__ be,
                  const float* __restrict__ wgt, const float* __restrict__ bias,
                  float* __restrict__ out, int Tout) {
  __shared__ unsigned short sv[64 * 66];
  __shared__ float wph[64 * 13];
  __shared__ float ssc[64], ssh[64];

  const int b = blockIdx.y;
  const int u0 = blockIdx.x * 64;
  const int Tin = Tout >> 2;
  const int tid = threadIdx.x;

  {
    int ci = tid >> 2, pp = tid & 3;
    float s0 = 0, s1 = 0, s2 = 0;
    #pragma unroll
    for (int k = 0; k < 7; ++k) {
      int d = (pp - 3 + k + 4) >> 2;
      float wv = wgt[ci * 7 + k];
      if (d == 0) s0 += wv; else if (d == 1) s1 += wv; else s2 += wv;
    }
    wph[ci * 13 + pp * 3 + 0] = s0;
    wph[ci * 13 + pp * 3 + 1] = s1;
    wph[ci * 13 + pp * 3 + 2] = s2;
  }
  if (tid < 64) {
    float S = sp[tid * 4] + sp[tid * 4 + 1] + sp[tid * 4 + 2] + sp[tid * 4 + 3];
    float Q = sp[256 + tid * 4] + sp[256 + tid * 4 + 1] + sp[256 + tid * 4 + 2] + sp[256 + tid * 4 + 3];
    float n = 4.f * (float)Tin;
    float mean = S / n;
    float var = Q / n - mean * mean;
    float sc = g[tid] * rsqrtf(var + 1e-5f);
    ssc[tid] = sc;
    ssh[tid] = be[tid] - mean * sc;
  }
  __syncthreads();

  const float* inb = csum_in + (long)b * 64 * Tin;
  for (int i = tid; i < 64 * 66; i += 256) {
    int ci = i / 66, uu = i - ci * 66;
    int u = u0 - 1 + uu;
    unsigned short v = 0;
    if (u >= 0 && u < Tin) {
      float t = inb[(long)ci * Tin + u];
      v = f2bf(leaky(t * ssc[ci] + ssh[ci]));
    }
    sv[ci * 66 + uu] = v;
  }
  __syncthreads();

  const int ul = tid >> 2;
  const int chunk = tid & 3;
  float a0 = 0, a1 = 0, a2 = 0, a3 = 0;
  #pragma unroll
  for (int cc = 0; cc < 16; ++cc) {
    int ci = chunk * 16 + cc;
    float v0 = bf2f(sv[ci * 66 + ul]);
    float v1 = bf2f(sv[ci * 66 + ul + 1]);
    float v2 = bf2f(sv[ci * 66 + ul + 2]);
    const float* wp = wph + ci * 13;
    a0 += v0 * wp[0] + v1 * wp[1];
    a1 += v0 * wp[3] + v1 * wp[4] + v2 * wp[5];
    a2 += v0 * wp[6] + v1 * wp[7] + v2 * wp[8];
    a3 += v1 * wp[10] + v2 * wp[11];
  }
  #pragma unroll
  for (int msk = 1; msk <= 2; msk <<= 1) {
    a0 += __shfl_xor(a0, msk);
    a1 += __shfl_xor(a1, msk);
    a2 += __shfl_xor(a2, msk);
    a3 += __shfl_xor(a3, msk);
  }
  if (chunk == 0) {
    float bv = bias[0];
    float4 r = make_float4(a0 + bv, a1 + bv, a2 + bv, a3 + bv);
    *(float4*)(out + (long)b * Tout + (long)(u0 + ul) * 4) = r;
  }
}

extern "C" void kernel_launch(void* const* d_in, const int* in_sizes, int n_in,
                              void* d_out, int out_size, void* d_ws, size_t ws_size,
                              hipStream_t stream) {
  const float* x     = (const float*)d_in[0];
  // d_in[1] = atoms: dead (sparse_code result unused by outputs)
  const float* ew    = (const float*)d_in[2];
  const float* eb    = (const float*)d_in[3];
  const float* w1    = (const float*)d_in[4];
  const float* b1    = (const float*)d_in[5];
  const float* g1    = (const float*)d_in[6];
  const float* be1   = (const float*)d_in[7];
  const float* w2    = (const float*)d_in[8];
  const float* b2    = (const float*)d_in[9];
  const float* g2    = (const float*)d_in[10];
  const float* be2   = (const float*)d_in[11];
  const float* w3    = (const float*)d_in[12];
  const float* b3    = (const float*)d_in[13];
  const float* up_w1 = (const float*)d_in[14];
  const float* up_b1 = (const float*)d_in[15];
  const float* bn_g1 = (const float*)d_in[16];
  const float* bn_b1 = (const float*)d_in[17];
  const float* up_w2 = (const float*)d_in[18];
  const float* up_b2 = (const float*)d_in[19];
  const float* bn_g2 = (const float*)d_in[20];
  const float* bn_b2 = (const float*)d_in[21];
  const float* up_w3 = (const float*)d_in[22];
  const float* up_b3 = (const float*)d_in[23];
  const float* bn_g3 = (const float*)d_in[24];
  const float* bn_b3 = (const float*)d_in[25];
  const float* up_w4 = (const float*)d_in[26];
  const float* up_b4 = (const float*)d_in[27];
  const float* bn_g4 = (const float*)d_in[28];
  const float* bn_b4 = (const float*)d_in[29];
  const float* up_w5 = (const float*)d_in[30];
  const float* up_b5 = (const float*)d_in[31];

  float* out = (float*)d_out;              // [0,131072) = y, [131072,135168) = ctx_out

  float* ws = (float*)d_ws;
  float* part   = ws;                      // 8192
  float* gpart  = part + 8192;             // 32768
  float* t2     = gpart + 32768;           // 4096
  float* statsp = t2 + 4096;               // 4096
  float* csum   = statsp + 4096;           // 2097152
  float* pbuf   = csum + 2097152;          // 4194304
  unsigned short* encbf = (unsigned short*)(pbuf + 4194304);  // 524288 u16
  unsigned short* wbuf  = encbf + 524288;  // 5734400 u16

  // 1: embed (direct-load MFMA, fused ctx partials) + weight packing riders
  embed_pack<<<3744, 256, 0, stream>>>(x, ew, eb, encbf, part,
                                       up_w1, up_w2, up_w3, up_w4, wbuf);

  // 2: conv stage 1 (SK=4, 32-t tiles) + MLP gemm1 rider
  conv1_g<4><<<768, 256, 24320, stream>>>(encbf, wbuf, pbuf,
                                          512, part, w1, gpart, 1);
  // 3: bnsum1 (SK=4) + lnsum1 rider (gpart -> t2)
  bnsum_ln<<<2052, 256, 0, stream>>>(pbuf, statsp, csum, 512, 128, 4, 1, 1,
                                     gpart, b1, g1, be1, t2);
  // 4: conv stage 2 (SK=4, 32-u tiles) + gemm2 rider (t2 -> gpart)
  conv_ph_g<4><<<512, 256, 10880, stream>>>(csum, statsp, bn_g1, bn_b1, wbuf + 3670016,
                                            pbuf, 512, 256, 128,
                                            256, t2, w2, gpart, 0);
  // 5: bnsum2 (SK=4) + lnsum2 rider (gpart -> t2)
  bnsum_ln<<<1028, 256, 0, stream>>>(pbuf, statsp, csum, 256, 512, 4, 1, 1,
                                     gpart, b2, g2, be2, t2);
  // 6: conv stage 3 (SK=2) + gemm3 rider (t2 -> gpart)
  conv_ph_g<2><<<512, 256, 10880, stream>>>(csum, statsp, bn_g2, bn_b2, wbuf + 5242880,
                                            pbuf, 256, 128, 512,
                                            256, t2, w3, gpart, 0);
  // 7: bnsum3 (SK=2) + fin rider (gpart -> ctx_out)
  bnsum_ln<<<528, 256, 0, stream>>>(pbuf, statsp, csum, 128, 2048, 2, 1, 2,
                                    gpart, b3, b3, b3, out + 131072);
  // 8: conv stage 4 (SK=1 -> writes final sums to pbuf directly)
  conv_ph_g<1><<<256, 256, 10880, stream>>>(csum, statsp, bn_g3, bn_b3, wbuf + 5636096,
                                            pbuf, 128, 64, 2048,
                                            256, t2, w3, gpart, -1);
  // 9: bnsum4 (SK=1, stats only - no copy)
  bnsum_ln<<<256, 256, 0, stream>>>(pbuf, statsp, csum, 64, 8192, 1, 0, 0,
                                    gpart, b3, b3, b3, out + 131072);
  // 10: conv stage 5 (reads pbuf directly)
  conv5_kernel<<<dim3(128, 4), 256, 0, stream>>>(pbuf, statsp, bn_g4, bn_b4, up_w5, up_b5, out, 32768);
}